// Round 7
// baseline (472.414 us; speedup 1.0000x reference)
//
#include <hip/hip_runtime.h>
#include <hip/hip_bf16.h>

#define BH   64
#define LSEQ 8192
#define DDIM 64
#define NPOS (BH * LSEQ)          // 524288 positions
#define NT4  (NPOS * DDIM / 4)    // 8388608 float4s in v/out

typedef __attribute__((ext_vector_type(8))) short bf16x8;
typedef __attribute__((ext_vector_type(4))) float f32x4;

// Native RNE f32->bf16 (compiler packs pairs into v_cvt_pk_bf16_f32).
__device__ inline short f2bf(float f) {
    __bf16 b = (__bf16)f;
    return __builtin_bit_cast(short, b);
}
__device__ inline float bf2f(short s) {
    unsigned u = ((unsigned)(unsigned short)s) << 16;
    return __builtin_bit_cast(float, u);
}
__device__ inline void split8(const float* f, bf16x8& hi, bf16x8& lo) {
#pragma unroll
    for (int j = 0; j < 8; j++) {
        short h = f2bf(f[j]);
        hi[j] = h;
        lo[j] = f2bf(f[j] - bf2f(h));
    }
}
__device__ inline float tanh_fast(float x) {
    float ex = __expf(2.f * x);
    return 1.f - 2.f * __builtin_amdgcn_rcpf(ex + 1.f);
}

// ---------------------------------------------------------------------------
// K1: e[p] = mask ? va.tanh(Wa q + Ua k + bias) + va_b : -10000
//
// v3 structure: 1 wave per block, 4 tiles (16 pos each) per wave.
// Global loads are LANE-LINEAR (lane l reads base+16*l -> 16 full cache
// lines per instruction; the old fragment-direct loads touched 32 half-used
// lines). Data is staged through a 2-buffer LDS tile with an XOR chunk
// swizzle (chunk' = chunk ^ (row&7)) applied on BOTH ds_write and ds_read,
// giving conflict-free b128 access in fragment order. The load->ds_write->
// ds_read->mfma memory dependences make the 2-tile prefetch pipeline
// un-flattenable by the compiler (register pipelines were flattened twice:
// VGPR 100/84 instead of 150+).
// ---------------------------------------------------------------------------
__global__ __launch_bounds__(64, 2) void score_kernel(
    const float* __restrict__ q, const float* __restrict__ k,
    const int*   __restrict__ mask,
    const float* __restrict__ Waw, const float* __restrict__ Wab,
    const float* __restrict__ Uaw, const float* __restrict__ Uab,
    const float* __restrict__ vaw, const float* __restrict__ vab_p,
    float* __restrict__ e_out)
{
    const int lane = threadIdx.x;        // 64-thread block = 1 wave
    const int m    = lane & 15;          // fragment row / output-feature lane
    const int g    = lane >> 4;          // fragment k-chunk
    const long t0  = (long)blockIdx.x * 4;

    __shared__ float lds[2][2048];       // [buf][ q: 0..1023 | k: 1024..2047 ]

    // per-wave constant weight fragments (bf16), biases, va
    bf16x8 bwa[4][2], bua[4][2];
    float bias_s[4], vav[4];
    float vab;

    float4 RA[8], RB[8];
    int4 mk0, mk1, mk2, mk3;

    // Lane-linear global load of one 16x64 q-tile + k-tile (8 KB).
    auto gload = [&](float4 (&R)[8], int4& mk, long tile) {
        mk = ((const int4*)mask)[tile * 4 + g];
        const float* qb = q + tile * 1024;
        const float* kb = k + tile * 1024;
#pragma unroll
        for (int i = 0; i < 4; i++)
            R[i]     = *((const float4*)(qb + i * 256 + lane * 4));
#pragma unroll
        for (int i = 0; i < 4; i++)
            R[4 + i] = *((const float4*)(kb + i * 256 + lane * 4));
    };

    // Swizzled LDS store: float idx = half*1024 + row*64 + ((c ^ (row&7))<<2)
    auto stage = [&](const float4 (&R)[8], int buf) {
#pragma unroll
        for (int i = 0; i < 8; i++) {
            const int row  = 4 * (i & 3) + g;
            const int half = i >> 2;
            float* dst = &lds[buf][half * 1024 + row * 64 + ((m ^ (row & 7)) << 2)];
            *((float4*)dst) = R[i];
        }
    };

    auto load_weights = [&]() {
#pragma unroll
        for (int t = 0; t < 4; t++) {
            const int n = t * 16 + m;
            bias_s[t] = Wab[n] + Uab[n];
            vav[t]    = vaw[n];
#pragma unroll
            for (int s = 0; s < 2; s++) {
                const int k0 = s * 32 + g * 8;
                const float4 wA = ((const float4*)(Waw + n * 64 + k0))[0];
                const float4 wB = ((const float4*)(Waw + n * 64 + k0))[1];
                const float4 uA = ((const float4*)(Uaw + n * 64 + k0))[0];
                const float4 uB = ((const float4*)(Uaw + n * 64 + k0))[1];
                float wf[8] = {wA.x, wA.y, wA.z, wA.w, wB.x, wB.y, wB.z, wB.w};
                float uf[8] = {uA.x, uA.y, uA.z, uA.w, uB.x, uB.y, uB.z, uB.w};
                bf16x8 wv, uv;
#pragma unroll
                for (int j = 0; j < 8; j++) { wv[j] = f2bf(wf[j]); uv[j] = f2bf(uf[j]); }
                bwa[t][s] = wv;
                bua[t][s] = uv;
            }
        }
        vab = vab_p[0];
    };

    // Read fragments (swizzled) from LDS, run the MFMA chain, reduce, store.
    auto compute = [&](int buf, const int4& mk, long tile) {
        f32x4 acc[4];
#pragma unroll
        for (int t = 0; t < 4; t++) acc[t] = (f32x4){0.f, 0.f, 0.f, 0.f};
        const float* L = lds[buf];
#pragma unroll
        for (int s = 0; s < 2; s++) {
            const int c0 = s * 8 + g * 2;
            const float4 qa = *((const float4*)(L + m * 64 + (( c0      ^ (m & 7)) << 2)));
            const float4 qb = *((const float4*)(L + m * 64 + (((c0 + 1) ^ (m & 7)) << 2)));
            const float4 ka = *((const float4*)(L + 1024 + m * 64 + (( c0      ^ (m & 7)) << 2)));
            const float4 kb = *((const float4*)(L + 1024 + m * 64 + (((c0 + 1) ^ (m & 7)) << 2)));
            float qf[8] = {qa.x, qa.y, qa.z, qa.w, qb.x, qb.y, qb.z, qb.w};
            float kf[8] = {ka.x, ka.y, ka.z, ka.w, kb.x, kb.y, kb.z, kb.w};
            bf16x8 qhi, qlo, khi, klo;
            split8(qf, qhi, qlo);
            split8(kf, khi, klo);
#pragma unroll
            for (int t = 0; t < 4; t++) {
                acc[t] = __builtin_amdgcn_mfma_f32_16x16x32_bf16(qhi, bwa[t][s], acc[t], 0, 0, 0);
                acc[t] = __builtin_amdgcn_mfma_f32_16x16x32_bf16(qlo, bwa[t][s], acc[t], 0, 0, 0);
                acc[t] = __builtin_amdgcn_mfma_f32_16x16x32_bf16(khi, bua[t][s], acc[t], 0, 0, 0);
                acc[t] = __builtin_amdgcn_mfma_f32_16x16x32_bf16(klo, bua[t][s], acc[t], 0, 0, 0);
            }
        }
        float c[4] = {0.f, 0.f, 0.f, 0.f};
#pragma unroll
        for (int t = 0; t < 4; t++) {
#pragma unroll
            for (int r = 0; r < 4; r++)
                c[r] += vav[t] * tanh_fast(acc[t][r] + bias_s[t]);
        }
#pragma unroll
        for (int r = 0; r < 4; r++) {
#pragma unroll
            for (int off2 = 1; off2 < 16; off2 <<= 1)
                c[r] += __shfl_xor(c[r], off2, 16);
        }
        if (m == 0) {
            float4 ev;
            ev.x = mk.x ? c[0] + vab : -10000.f;
            ev.y = mk.y ? c[1] + vab : -10000.f;
            ev.z = mk.z ? c[2] + vab : -10000.f;
            ev.w = mk.w ? c[3] + vab : -10000.f;
            *((float4*)(e_out + tile * 16 + g * 4)) = ev;
        }
    };

    // 2-tile-deep pipeline, enforced by memory deps (not register liveness):
    gload(RA, mk0, t0 + 0);
    gload(RB, mk1, t0 + 1);
    load_weights();               // L2-hit weight loads hide t0/t1 HBM latency
    stage(RA, 0);                 // waits RA, frees RA regs
    gload(RA, mk2, t0 + 2);
    // tile 0
    stage(RB, 1);
    gload(RB, mk3, t0 + 3);
    compute(0, mk0, t0 + 0);
    // tile 1
    stage(RA, 0);                 // DS ops in-order per wave: safe after reads
    compute(1, mk1, t0 + 1);
    // tile 2
    stage(RB, 1);
    compute(0, mk2, t0 + 2);
    // tile 3
    compute(1, mk3, t0 + 3);
}

// ---------------------------------------------------------------------------
// K2: per-row stats: M = max(e), invS = 1/sum(exp(e-M)). Mask already in e.
// ---------------------------------------------------------------------------
__global__ __launch_bounds__(1024) void rowstat_kernel(
    const float* __restrict__ e, float* __restrict__ stats)
{
    const int row = blockIdx.x;
    const size_t base = (size_t)row * LSEQ;
    const int tid  = threadIdx.x;
    const int lane = tid & 63;
    const int wv   = tid >> 6;
    __shared__ float redmax[16];
    __shared__ float redsum[16];

    float4 e0 = ((const float4*)(e + base))[tid];
    float4 e1 = ((const float4*)(e + base))[1024 + tid];
    float em[8] = {e0.x, e0.y, e0.z, e0.w, e1.x, e1.y, e1.z, e1.w};

    float lm = em[0];
#pragma unroll
    for (int j = 1; j < 8; j++) lm = fmaxf(lm, em[j]);
#pragma unroll
    for (int off = 32; off >= 1; off >>= 1) lm = fmaxf(lm, __shfl_xor(lm, off, 64));
    if (lane == 0) redmax[wv] = lm;
    __syncthreads();
    float M = redmax[0];
#pragma unroll
    for (int i = 1; i < 16; i++) M = fmaxf(M, redmax[i]);

    float ls = 0.f;
#pragma unroll
    for (int j = 0; j < 8; j++) ls += __expf(em[j] - M);
#pragma unroll
    for (int off = 32; off >= 1; off >>= 1) ls += __shfl_xor(ls, off, 64);
    if (lane == 0) redsum[wv] = ls;
    __syncthreads();
    if (tid == 0) {
        float S = 0.f;
#pragma unroll
        for (int i = 0; i < 16; i++) S += redsum[i];
        stats[row * 2]     = M;
        stats[row * 2 + 1] = 1.f / S;
    }
}

// ---------------------------------------------------------------------------
// K3: out[p][d] = exp(e[p]-M[row])*invS[row] * v[p][d].
// 4 independent float4 per thread; nontemporal on the 256 MB v/out streams.
// ---------------------------------------------------------------------------
__global__ __launch_bounds__(256) void scale_kernel(
    const float* __restrict__ v, const float* __restrict__ e,
    const float* __restrict__ stats, float* __restrict__ out)
{
    const size_t b0 = (size_t)blockIdx.x * 1024 + threadIdx.x;
    const f32x4* vp = (const f32x4*)v;
    f32x4*       op = (f32x4*)out;

    size_t idx[4];
    f32x4  vv[4];
    float  ee[4];
    float2 st[4];
#pragma unroll
    for (int j = 0; j < 4; j++) {
        idx[j] = b0 + (size_t)j * 256;
        vv[j]  = __builtin_nontemporal_load(vp + idx[j]);
    }
#pragma unroll
    for (int j = 0; j < 4; j++) {
        const size_t p = idx[j] >> 4;
        ee[j] = e[p];
        st[j] = ((const float2*)stats)[p >> 13];
    }
#pragma unroll
    for (int j = 0; j < 4; j++) {
        const float a = __expf(ee[j] - st[j].x) * st[j].y;
        f32x4 o = vv[j] * a;
        __builtin_nontemporal_store(o, op + idx[j]);
    }
}

extern "C" void kernel_launch(void* const* d_in, const int* in_sizes, int n_in,
                              void* d_out, int out_size, void* d_ws, size_t ws_size,
                              hipStream_t stream) {
    const float* q    = (const float*)d_in[0];
    const float* k    = (const float*)d_in[1];
    const float* v    = (const float*)d_in[2];
    const int*   mask = (const int*)d_in[3];
    const float* Waw  = (const float*)d_in[4];
    const float* Wab  = (const float*)d_in[5];
    const float* Uaw  = (const float*)d_in[6];
    const float* Uab  = (const float*)d_in[7];
    const float* vaw  = (const float*)d_in[8];
    const float* vab  = (const float*)d_in[9];
    float* out = (float*)d_out;

    float* e_buf = (float*)d_ws;                  // NPOS floats (2 MB)
    float* stats = (float*)d_ws + NPOS;           // 128 floats (M, invS per row)

    score_kernel<<<NPOS / 64, 64, 0, stream>>>(q, k, mask, Waw, Wab, Uaw, Uab, vaw, vab, e_buf);
    rowstat_kernel<<<BH, 1024, 0, stream>>>(e_buf, stats);
    scale_kernel<<<NT4 / 1024, 256, 0, stream>>>(v, e_buf, stats, out);
}

// Round 11
// 414.280 us; speedup vs baseline: 1.1403x; 1.1403x over previous
//
#include <hip/hip_runtime.h>
#include <hip/hip_bf16.h>

#define BH   64
#define LSEQ 8192
#define DDIM 64
#define NPOS (BH * LSEQ)          // 524288 positions
#define NT4  (NPOS * DDIM / 4)    // 8388608 float4s in v/out

typedef __attribute__((ext_vector_type(8))) short bf16x8;
typedef __attribute__((ext_vector_type(4))) float f32x4;

// Native RNE f32->bf16 (compiler packs pairs into v_cvt_pk_bf16_f32).
__device__ inline short f2bf(float f) {
    __bf16 b = (__bf16)f;
    return __builtin_bit_cast(short, b);
}
__device__ inline float bf2f(short s) {
    unsigned u = ((unsigned)(unsigned short)s) << 16;
    return __builtin_bit_cast(float, u);
}
__device__ inline void split8(const float* f, bf16x8& hi, bf16x8& lo) {
#pragma unroll
    for (int j = 0; j < 8; j++) {
        short h = f2bf(f[j]);
        hi[j] = h;
        lo[j] = f2bf(f[j] - bf2f(h));
    }
}
__device__ inline float tanh_fast(float x) {
    float ex = __expf(2.f * x);
    return 1.f - 2.f * __builtin_amdgcn_rcpf(ex + 1.f);
}

// ---------------------------------------------------------------------------
// K1: e[p] = mask ? va.tanh(Wa q + Ua k + bias) + va_b : -10000
//
// v4: global_load_lds DMA staging (no register intermediary -> no scratch).
// v3's register staging went to scratch: WRITE_SIZE showed 264 MB of HBM
// writes (= 64 spilled VGPRs x 8 KB/block x 8192 blocks), VGPR=92.
// DMA writes LDS linearly (wave-uniform base + lane*16); the XOR swizzle is
// applied to the per-lane GLOBAL source address instead (rule-21 pattern:
// source permutation == read permutation, both c ^= row&7). Per DMA call the
// wave still covers 4 complete rows = 16 full cache lines (coalesced).
// 2-buffer LDS pipeline with counted s_waitcnt vmcnt(N) (never 0 mid-loop):
// between consecutive waits sit exactly 8 DMAs + 1 e-store => vmcnt(9).
// compute() is byte-identical to the v3 version that passed correctness.
// ---------------------------------------------------------------------------
__global__ __launch_bounds__(64, 2) void score_kernel(
    const float* __restrict__ q, const float* __restrict__ k,
    const int*   __restrict__ mask,
    const float* __restrict__ Waw, const float* __restrict__ Wab,
    const float* __restrict__ Uaw, const float* __restrict__ Uab,
    const float* __restrict__ vaw, const float* __restrict__ vab_p,
    float* __restrict__ e_out)
{
    const int lane = threadIdx.x;        // 64-thread block = 1 wave
    const int m    = lane & 15;          // fragment row / output-feature lane
    const int g    = lane >> 4;          // fragment k-chunk group
    const long t0  = (long)blockIdx.x * 4;

    __shared__ float lds[2][2048];       // [buf][ q: 0..1023 | k: 1024..2047 ]

    // ---- prologue: weights + masks into registers FIRST (so the compiler's
    // weight-waits don't interleave with the DMA vmcnt bookkeeping) ----
    bf16x8 bwa[4][2], bua[4][2];
    float bias_s[4], vav[4];
#pragma unroll
    for (int t = 0; t < 4; t++) {
        const int n = t * 16 + m;
        bias_s[t] = Wab[n] + Uab[n];
        vav[t]    = vaw[n];
#pragma unroll
        for (int s = 0; s < 2; s++) {
            const int k0 = s * 32 + g * 8;
            const float4 wA = ((const float4*)(Waw + n * 64 + k0))[0];
            const float4 wB = ((const float4*)(Waw + n * 64 + k0))[1];
            const float4 uA = ((const float4*)(Uaw + n * 64 + k0))[0];
            const float4 uB = ((const float4*)(Uaw + n * 64 + k0))[1];
            float wf[8] = {wA.x, wA.y, wA.z, wA.w, wB.x, wB.y, wB.z, wB.w};
            float uf[8] = {uA.x, uA.y, uA.z, uA.w, uB.x, uB.y, uB.z, uB.w};
            bf16x8 wv, uv;
#pragma unroll
            for (int j = 0; j < 8; j++) { wv[j] = f2bf(wf[j]); uv[j] = f2bf(uf[j]); }
            bwa[t][s] = wv;
            bua[t][s] = uv;
        }
    }
    const float vab = vab_p[0];
    const int4 mk0 = ((const int4*)mask)[(t0 + 0) * 4 + g];
    const int4 mk1 = ((const int4*)mask)[(t0 + 1) * 4 + g];
    const int4 mk2 = ((const int4*)mask)[(t0 + 2) * 4 + g];
    const int4 mk3 = ((const int4*)mask)[(t0 + 3) * 4 + g];

    // DMA one q+k tile pair (8 KB) into buf: 8 x global_load_lds(16B).
    // LDS is written linearly (slot = call_base + lane); the source address
    // carries the swizzle: row = 4i+g, chunk = m ^ (row&7).
    auto issue_tile = [&](long tile, int buf) {
        const float* qb = q + tile * 1024;
        const float* kb = k + tile * 1024;
#pragma unroll
        for (int i = 0; i < 4; i++) {
            const int row = 4 * i + g;
            const int c   = m ^ (row & 7);
            __builtin_amdgcn_global_load_lds(
                (const __attribute__((address_space(1))) void*)(qb + row * 64 + c * 4),
                (__attribute__((address_space(3))) void*)(&lds[buf][i * 256]),
                16, 0, 0);
            __builtin_amdgcn_global_load_lds(
                (const __attribute__((address_space(1))) void*)(kb + row * 64 + c * 4),
                (__attribute__((address_space(3))) void*)(&lds[buf][1024 + i * 256]),
                16, 0, 0);
        }
    };

    // Read fragments (swizzled) from LDS, MFMA chain, reduce, store.
    // Identical to the round-7 version that passed correctness.
    auto compute = [&](int buf, const int4& mk, long tile) {
        f32x4 acc[4];
#pragma unroll
        for (int t = 0; t < 4; t++) acc[t] = (f32x4){0.f, 0.f, 0.f, 0.f};
        const float* L = lds[buf];
#pragma unroll
        for (int s = 0; s < 2; s++) {
            const int c0 = s * 8 + g * 2;
            const float4 qa = *((const float4*)(L + m * 64 + (( c0      ^ (m & 7)) << 2)));
            const float4 qb = *((const float4*)(L + m * 64 + (((c0 + 1) ^ (m & 7)) << 2)));
            const float4 ka = *((const float4*)(L + 1024 + m * 64 + (( c0      ^ (m & 7)) << 2)));
            const float4 kb = *((const float4*)(L + 1024 + m * 64 + (((c0 + 1) ^ (m & 7)) << 2)));
            float qf[8] = {qa.x, qa.y, qa.z, qa.w, qb.x, qb.y, qb.z, qb.w};
            float kf[8] = {ka.x, ka.y, ka.z, ka.w, kb.x, kb.y, kb.z, kb.w};
            bf16x8 qhi, qlo, khi, klo;
            split8(qf, qhi, qlo);
            split8(kf, khi, klo);
#pragma unroll
            for (int t = 0; t < 4; t++) {
                acc[t] = __builtin_amdgcn_mfma_f32_16x16x32_bf16(qhi, bwa[t][s], acc[t], 0, 0, 0);
                acc[t] = __builtin_amdgcn_mfma_f32_16x16x32_bf16(qlo, bwa[t][s], acc[t], 0, 0, 0);
                acc[t] = __builtin_amdgcn_mfma_f32_16x16x32_bf16(khi, bua[t][s], acc[t], 0, 0, 0);
                acc[t] = __builtin_amdgcn_mfma_f32_16x16x32_bf16(klo, bua[t][s], acc[t], 0, 0, 0);
            }
        }
        float c[4] = {0.f, 0.f, 0.f, 0.f};
#pragma unroll
        for (int t = 0; t < 4; t++) {
#pragma unroll
            for (int r = 0; r < 4; r++)
                c[r] += vav[t] * tanh_fast(acc[t][r] + bias_s[t]);
        }
#pragma unroll
        for (int r = 0; r < 4; r++) {
#pragma unroll
            for (int off2 = 1; off2 < 16; off2 <<= 1)
                c[r] += __shfl_xor(c[r], off2, 16);
        }
        if (m == 0) {
            float4 ev;
            ev.x = mk.x ? c[0] + vab : -10000.f;
            ev.y = mk.y ? c[1] + vab : -10000.f;
            ev.z = mk.z ? c[2] + vab : -10000.f;
            ev.w = mk.w ? c[3] + vab : -10000.f;
            *((float4*)(e_out + tile * 16 + g * 4)) = ev;
        }
    };

    // ---- 2-buffer DMA pipeline with counted vmcnt ----
    issue_tile(t0 + 0, 0);                       // L0: 8 DMAs
    issue_tile(t0 + 1, 1);                       // L1: 8 DMAs
    asm volatile("s_waitcnt vmcnt(8)" ::: "memory");   // L0 done, L1 may fly
    __builtin_amdgcn_sched_barrier(0);
    compute(0, mk0, t0 + 0);                     // + 1 e-store
    issue_tile(t0 + 2, 0);                       // L2: 8 DMAs (buf0 reads done)
    asm volatile("s_waitcnt vmcnt(9)" ::: "memory");   // allow store0+L2 => L1 done
    __builtin_amdgcn_sched_barrier(0);
    compute(1, mk1, t0 + 1);
    issue_tile(t0 + 3, 1);                       // L3
    asm volatile("s_waitcnt vmcnt(9)" ::: "memory");   // allow store1+L3 => L2 done
    __builtin_amdgcn_sched_barrier(0);
    compute(0, mk2, t0 + 2);
    asm volatile("s_waitcnt vmcnt(1)" ::: "memory");   // allow store2 => L3 done
    __builtin_amdgcn_sched_barrier(0);
    compute(1, mk3, t0 + 3);
}

// ---------------------------------------------------------------------------
// K2: per-row stats: M = max(e), invS = 1/sum(exp(e-M)). Mask already in e.
// ---------------------------------------------------------------------------
__global__ __launch_bounds__(1024) void rowstat_kernel(
    const float* __restrict__ e, float* __restrict__ stats)
{
    const int row = blockIdx.x;
    const size_t base = (size_t)row * LSEQ;
    const int tid  = threadIdx.x;
    const int lane = tid & 63;
    const int wv   = tid >> 6;
    __shared__ float redmax[16];
    __shared__ float redsum[16];

    float4 e0 = ((const float4*)(e + base))[tid];
    float4 e1 = ((const float4*)(e + base))[1024 + tid];
    float em[8] = {e0.x, e0.y, e0.z, e0.w, e1.x, e1.y, e1.z, e1.w};

    float lm = em[0];
#pragma unroll
    for (int j = 1; j < 8; j++) lm = fmaxf(lm, em[j]);
#pragma unroll
    for (int off = 32; off >= 1; off >>= 1) lm = fmaxf(lm, __shfl_xor(lm, off, 64));
    if (lane == 0) redmax[wv] = lm;
    __syncthreads();
    float M = redmax[0];
#pragma unroll
    for (int i = 1; i < 16; i++) M = fmaxf(M, redmax[i]);

    float ls = 0.f;
#pragma unroll
    for (int j = 0; j < 8; j++) ls += __expf(em[j] - M);
#pragma unroll
    for (int off = 32; off >= 1; off >>= 1) ls += __shfl_xor(ls, off, 64);
    if (lane == 0) redsum[wv] = ls;
    __syncthreads();
    if (tid == 0) {
        float S = 0.f;
#pragma unroll
        for (int i = 0; i < 16; i++) S += redsum[i];
        stats[row * 2]     = M;
        stats[row * 2 + 1] = 1.f / S;
    }
}

// ---------------------------------------------------------------------------
// K3: out[p][d] = exp(e[p]-M[row])*invS[row] * v[p][d].
// 4 independent float4 per thread; nontemporal on the 256 MB v/out streams.
// ---------------------------------------------------------------------------
__global__ __launch_bounds__(256) void scale_kernel(
    const float* __restrict__ v, const float* __restrict__ e,
    const float* __restrict__ stats, float* __restrict__ out)
{
    const size_t b0 = (size_t)blockIdx.x * 1024 + threadIdx.x;
    const f32x4* vp = (const f32x4*)v;
    f32x4*       op = (f32x4*)out;

    size_t idx[4];
    f32x4  vv[4];
    float  ee[4];
    float2 st[4];
#pragma unroll
    for (int j = 0; j < 4; j++) {
        idx[j] = b0 + (size_t)j * 256;
        vv[j]  = __builtin_nontemporal_load(vp + idx[j]);
    }
#pragma unroll
    for (int j = 0; j < 4; j++) {
        const size_t p = idx[j] >> 4;
        ee[j] = e[p];
        st[j] = ((const float2*)stats)[p >> 13];
    }
#pragma unroll
    for (int j = 0; j < 4; j++) {
        const float a = __expf(ee[j] - st[j].x) * st[j].y;
        f32x4 o = vv[j] * a;
        __builtin_nontemporal_store(o, op + idx[j]);
    }
}

extern "C" void kernel_launch(void* const* d_in, const int* in_sizes, int n_in,
                              void* d_out, int out_size, void* d_ws, size_t ws_size,
                              hipStream_t stream) {
    const float* q    = (const float*)d_in[0];
    const float* k    = (const float*)d_in[1];
    const float* v    = (const float*)d_in[2];
    const int*   mask = (const int*)d_in[3];
    const float* Waw  = (const float*)d_in[4];
    const float* Wab  = (const float*)d_in[5];
    const float* Uaw  = (const float*)d_in[6];
    const float* Uab  = (const float*)d_in[7];
    const float* vaw  = (const float*)d_in[8];
    const float* vab  = (const float*)d_in[9];
    float* out = (float*)d_out;

    float* e_buf = (float*)d_ws;                  // NPOS floats (2 MB)
    float* stats = (float*)d_ws + NPOS;           // 128 floats (M, invS per row)

    score_kernel<<<NPOS / 64, 64, 0, stream>>>(q, k, mask, Waw, Wab, Uaw, Uab, vaw, vab, e_buf);
    rowstat_kernel<<<BH, 1024, 0, stream>>>(e_buf, stats);
    scale_kernel<<<NT4 / 1024, 256, 0, stream>>>(v, e_buf, stats, out);
}